// Round 3
// baseline (391.351 us; speedup 1.0000x reference)
//
#include <hip/hip_runtime.h>
#include <stdint.h>

typedef unsigned short u16;
typedef short s16x8 __attribute__((ext_vector_type(8)));
typedef unsigned short u16x8 __attribute__((ext_vector_type(8)));
typedef float f32x4 __attribute__((ext_vector_type(4)));

#define GLD16(g, l) __builtin_amdgcn_global_load_lds( \
    (const __attribute__((address_space(1))) uint32_t*)(g), \
    (__attribute__((address_space(3))) uint32_t*)(l), 16, 0, 0)

__device__ __forceinline__ u16 f2bf(float f) {
  uint32_t u = __builtin_bit_cast(uint32_t, f);
  u += 0x7fffu + ((u >> 16) & 1u);
  return (u16)(u >> 16);
}

// ---------------- cast x (f32 -> bf16), 8 elems/thread ----------------
__global__ void cvt_kernel(const float* __restrict__ in, u16* __restrict__ out) {
  int i = blockIdx.x * 256 + threadIdx.x;
  const float4* p = (const float4*)in + (size_t)i * 2;
  float4 a = p[0], b = p[1];
  u16x8 o;
  o[0] = f2bf(a.x); o[1] = f2bf(a.y); o[2] = f2bf(a.z); o[3] = f2bf(a.w);
  o[4] = f2bf(b.x); o[5] = f2bf(b.y); o[6] = f2bf(b.z); o[7] = f2bf(b.w);
  *((u16x8*)out + i) = o;
}

// ------------- transpose f32 [bz][R][C] -> bf16 [bz][C][R] -------------
__global__ void transpose_f2b(const float* __restrict__ in, u16* __restrict__ out,
                              int R, int C) {
  __shared__ float tile[32][33];
  const int bz = blockIdx.z;
  in  += (size_t)bz * R * C;
  out += (size_t)bz * R * C;
  int c0 = blockIdx.x * 32, r0 = blockIdx.y * 32;
  int tx = threadIdx.x, ty = threadIdx.y;
  #pragma unroll
  for (int i = 0; i < 32; i += 8)
    tile[ty + i][tx] = in[(size_t)(r0 + ty + i) * C + c0 + tx];
  __syncthreads();
  #pragma unroll
  for (int i = 0; i < 32; i += 8)
    out[(size_t)(c0 + ty + i) * R + r0 + tx] = f2bf(tile[tx][ty + i]);
}

// ------------- transpose bf16 [bz][R][C] -> bf16 [bz][C][R] ------------
__global__ void transpose_b2b(const u16* __restrict__ in, u16* __restrict__ out,
                              int R, int C) {
  __shared__ u16 tile[32][33];
  const int bz = blockIdx.z;
  in  += (size_t)bz * R * C;
  out += (size_t)bz * R * C;
  int c0 = blockIdx.x * 32, r0 = blockIdx.y * 32;
  int tx = threadIdx.x, ty = threadIdx.y;
  #pragma unroll
  for (int i = 0; i < 32; i += 8)
    tile[ty + i][tx] = in[(size_t)(r0 + ty + i) * C + c0 + tx];
  __syncthreads();
  #pragma unroll
  for (int i = 0; i < 32; i += 8)
    out[(size_t)(c0 + ty + i) * R + r0 + tx] = tile[tx][ty + i];
}

// ---------------- 128x128x64 bf16 MFMA GEMM (m97 structure) ----------------
// A [M][K] bf16 row-major, Bt [N][K] bf16 (B transposed). EPI 0: qkv epilogue,
// EPI 1: f32 out + bias.
template <int EPI>
__global__ __launch_bounds__(256) void gemm128(
    const u16* __restrict__ A, const u16* __restrict__ Bt, int K,
    const float* __restrict__ bias,
    u16* __restrict__ kb, u16* __restrict__ qb, u16* __restrict__ vb,
    float* __restrict__ fout) {
  __shared__ __align__(16) u16 As[128 * 64];
  __shared__ __align__(16) u16 Bs[128 * 64];
  const int tid = threadIdx.x;
  const int lane = tid & 63;
  const int wr = (tid >> 6) >> 1, wc = (tid >> 6) & 1;
  const int row0 = blockIdx.y * 128, col0 = blockIdx.x * 128;
  const int l15 = lane & 15, l4 = lane >> 4;
  const u16* Ablk = A + (size_t)row0 * K;
  const u16* Bblk = Bt + (size_t)col0 * K;
  f32x4 acc[4][4] = {};
  for (int k0 = 0; k0 < K; k0 += 64) {
    #pragma unroll
    for (int i = 0; i < 4; i++) {
      int off = (i * 256 + tid) * 8;
      int r = off >> 6, c = off & 63;
      GLD16(Ablk + (size_t)r * K + k0 + c, As + off);
    }
    #pragma unroll
    for (int i = 0; i < 4; i++) {
      int off = (i * 256 + tid) * 8;
      int r = off >> 6, c = off & 63;
      GLD16(Bblk + (size_t)r * K + k0 + c, Bs + off);
    }
    __syncthreads();
    #pragma unroll
    for (int kc = 0; kc < 2; kc++) {
      s16x8 af[4], bfr[4];
      #pragma unroll
      for (int m = 0; m < 4; m++)
        af[m] = *(const s16x8*)(As + (wr * 64 + m * 16 + l15) * 64 + kc * 32 + l4 * 8);
      #pragma unroll
      for (int n = 0; n < 4; n++)
        bfr[n] = *(const s16x8*)(Bs + (wc * 64 + n * 16 + l15) * 64 + kc * 32 + l4 * 8);
      #pragma unroll
      for (int m = 0; m < 4; m++)
        #pragma unroll
        for (int n = 0; n < 4; n++)
          acc[m][n] = __builtin_amdgcn_mfma_f32_16x16x32_bf16(af[m], bfr[n], acc[m][n], 0, 0, 0);
    }
    __syncthreads();
  }
  const int rbase = row0 + wr * 64;
  const int cbase = col0 + wc * 64;
  if (EPI == 0) {
    // columns map: h = c/192; c%192 in [0,64)->k, [64,128)->q, [128,192)->v
    #pragma unroll
    for (int n = 0; n < 4; n++) {
      int c = cbase + n * 16 + l15;
      int h = c / 192, rr = c % 192;
      int part = rr >> 6, d = rr & 63;
      float bv = bias[h * 192 + rr];
      u16* dst = (part == 0) ? kb : (part == 1) ? qb : vb;
      // fold 1/sqrt(hd) AND log2(e) (for exp2-based softmax) into q
      float sc = (part == 1) ? 0.125f * 1.44269504f : 1.0f;
      #pragma unroll
      for (int m = 0; m < 4; m++)
        #pragma unroll
        for (int i = 0; i < 4; i++) {
          int r = rbase + m * 16 + l4 * 4 + i;
          int b = r >> 11, nn = r & 2047;
          dst[(((size_t)(b * 16 + h) * 2048 + nn) << 6) + d] = f2bf((acc[m][n][i] + bv) * sc);
        }
    }
  } else {
    #pragma unroll
    for (int n = 0; n < 4; n++) {
      int c = cbase + n * 16 + l15;
      float bv = bias[c];
      #pragma unroll
      for (int m = 0; m < 4; m++)
        #pragma unroll
        for (int i = 0; i < 4; i++) {
          int r = rbase + m * 16 + l4 * 4 + i;
          fout[(size_t)r * 1024 + c] = acc[m][n][i] + bv;
        }
    }
  }
}

// ---------------- causal flash attention (v2) ----------------
// Barrier-free: K/V fragments read directly from global (K/V are L2-resident,
// 256KB per bh, reused by all q-tiles of that bh). No LDS staging, no
// __syncthreads. Each WAVE independently grabs a work unit (one 16-row
// q-subtile of one bh) from a global atomic counter, in descending-work order
// so big units start first regardless of dispatch mapping.
// q,k: [BH=32][2048][64] bf16 (q pre-scaled by 0.125*log2e); vt: [32][64][2048]
// sa out: [B=2][2048][1024] bf16 (concat heads)
__global__ __launch_bounds__(256) void attn_kernel(
    const u16* __restrict__ q, const u16* __restrict__ k,
    const u16* __restrict__ vt, u16* __restrict__ sa,
    uint32_t* __restrict__ ctr) {
  // per-wave P re-layout buffer; stride 72 u16 = 144B (16B-aligned, ~2-way banks)
  __shared__ __align__(16) u16 Ps[4][16][72];
  const int tid = threadIdx.x;
  const int lane = tid & 63;
  const int wave = tid >> 6;
  const int l15 = lane & 15, l4 = lane >> 4;

  for (;;) {
    uint32_t u = 0;
    if (lane == 0) u = atomicAdd(ctr, 1u);
    u = (uint32_t)__shfl((int)u, 0);
    if (u >= 4096u) break;
    const int bh = (int)(u & 31u);
    const int tile = 127 - (int)(u >> 5);  // descending row base = more work first
    const int r0 = tile * 16;
    const int ktmax = (r0 + 15) >> 6;

    // Q fragments: A-frag row = l15 (q row r0+l15), k = 8*l4+j (+32 for qf1)
    const u16* qrow = q + (((size_t)bh * 2048 + r0 + l15) << 6);
    s16x8 qf0 = *(const s16x8*)(qrow + l4 * 8);
    s16x8 qf1 = *(const s16x8*)(qrow + 32 + l4 * 8);

    f32x4 o[4] = {};
    float mrow[4], lrow[4];
    #pragma unroll
    for (int r = 0; r < 4; r++) { mrow[r] = -3e38f; lrow[r] = 0.f; }

    const u16* kbh = k + (((size_t)bh * 2048) << 6);
    const u16* vbh = vt + (size_t)bh * 64 * 2048;

    for (int kt = 0; kt <= ktmax; kt++) {
      // S = Q K^T : B-frag rows (kv) straight from global (L2-hit, coalesced)
      f32x4 s[4] = {};
      #pragma unroll
      for (int t = 0; t < 4; t++) {
        const u16* kr = kbh + ((kt * 64 + t * 16 + l15) << 6);
        s16x8 kf0 = *(const s16x8*)(kr + l4 * 8);
        s16x8 kf1 = *(const s16x8*)(kr + 32 + l4 * 8);
        s[t] = __builtin_amdgcn_mfma_f32_16x16x32_bf16(qf0, kf0, s[t], 0, 0, 0);
        s[t] = __builtin_amdgcn_mfma_f32_16x16x32_bf16(qf1, kf1, s[t], 0, 0, 0);
      }
      // causal mask on last tile only (global indices)
      if (kt == ktmax) {
        #pragma unroll
        for (int t = 0; t < 4; t++)
          #pragma unroll
          for (int i = 0; i < 4; i++)
            if (kt * 64 + t * 16 + l15 > r0 + l4 * 4 + i) s[t][i] = -3e38f;
      }
      // online softmax per row (rows live in 16-lane groups); exp2 domain
      float p[4][4];
      #pragma unroll
      for (int r = 0; r < 4; r++) {
        float sm = fmaxf(fmaxf(s[0][r], s[1][r]), fmaxf(s[2][r], s[3][r]));
        #pragma unroll
        for (int off = 1; off < 16; off <<= 1)
          sm = fmaxf(sm, __shfl_xor(sm, off));
        float mn = fmaxf(mrow[r], sm);
        float alpha = exp2f(mrow[r] - mn);
        mrow[r] = mn;
        float rs = 0.f;
        #pragma unroll
        for (int t = 0; t < 4; t++) {
          float pv = exp2f(s[t][r] - mn);
          p[t][r] = pv;
          rs += pv;
        }
        #pragma unroll
        for (int off = 1; off < 16; off <<= 1)
          rs += __shfl_xor(rs, off);
        lrow[r] = lrow[r] * alpha + rs;
        #pragma unroll
        for (int t = 0; t < 4; t++) o[t][r] *= alpha;
      }
      // P (D-layout) -> LDS -> A-frag layout (per-wave, no barrier needed)
      #pragma unroll
      for (int t = 0; t < 4; t++)
        #pragma unroll
        for (int r = 0; r < 4; r++)
          Ps[wave][l4 * 4 + r][t * 16 + l15] = f2bf(p[t][r]);
      s16x8 pa0 = *(const s16x8*)&Ps[wave][l15][l4 * 8];
      s16x8 pa1 = *(const s16x8*)&Ps[wave][l15][32 + l4 * 8];
      // O += P V : V B-frag rows (d) straight from global VT
      #pragma unroll
      for (int t = 0; t < 4; t++) {
        const u16* vr = vbh + (size_t)(t * 16 + l15) * 2048 + kt * 64;
        s16x8 vf0 = *(const s16x8*)(vr + l4 * 8);
        s16x8 vf1 = *(const s16x8*)(vr + 32 + l4 * 8);
        o[t] = __builtin_amdgcn_mfma_f32_16x16x32_bf16(pa0, vf0, o[t], 0, 0, 0);
        o[t] = __builtin_amdgcn_mfma_f32_16x16x32_bf16(pa1, vf1, o[t], 0, 0, 0);
      }
    }
    // epilogue: normalize, write sa[b][n][h*64 + d] bf16
    const int b = bh >> 4, h = bh & 15;
    #pragma unroll
    for (int r = 0; r < 4; r++) {
      float inv = 1.f / lrow[r];
      int n = r0 + l4 * 4 + r;
      u16* dst = sa + ((size_t)(b * 2048 + n) << 10) + h * 64;
      #pragma unroll
      for (int t = 0; t < 4; t++)
        dst[t * 16 + l15] = f2bf(o[t][r] * inv);
    }
  }
}

extern "C" void kernel_launch(void* const* d_in, const int* in_sizes, int n_in,
                              void* d_out, int out_size, void* d_ws, size_t ws_size,
                              hipStream_t stream) {
  const float* x    = (const float*)d_in[0];
  const float* Wqkv = (const float*)d_in[1];
  const float* bqkv = (const float*)d_in[2];
  const float* Wo   = (const float*)d_in[3];
  const float* bo   = (const float*)d_in[4];
  float* out = (float*)d_out;

  // workspace carve (u16 elements)
  u16* xb  = (u16*)d_ws;          // [4096][1024] (reused as sab after qkv gemm)
  u16* wqt = xb + 4194304;        // [16*192][1024]  (B^T for qkv gemm)
  u16* wot = wqt + 3145728;       // [1024][1024]    (B^T for out gemm)
  u16* qb  = wot + 1048576;       // [32][2048][64]
  u16* kb  = qb + 4194304;
  u16* vb  = kb + 4194304;
  u16* vtb = vb + 4194304;        // [32][64][2048]
  u16* sab = xb;                  // alias: x's bf16 copy is dead after qkv gemm
  uint32_t* ctr = (uint32_t*)wqt; // alias: wqt dead after qkv gemm (work counter)

  cvt_kernel<<<2048, 256, 0, stream>>>(x, xb);
  transpose_f2b<<<dim3(6, 32, 16), dim3(32, 8), 0, stream>>>(Wqkv, wqt, 1024, 192);
  transpose_f2b<<<dim3(32, 32, 1), dim3(32, 8), 0, stream>>>(Wo, wot, 1024, 1024);
  gemm128<0><<<dim3(24, 32), 256, 0, stream>>>(xb, wqt, 1024, bqkv, kb, qb, vb, nullptr);
  transpose_b2b<<<dim3(2, 64, 32), dim3(32, 8), 0, stream>>>(vb, vtb, 2048, 64);
  hipMemsetAsync(ctr, 0, sizeof(uint32_t), stream);
  attn_kernel<<<dim3(1024), 256, 0, stream>>>(qb, kb, vtb, sab, ctr);
  gemm128<1><<<dim3(8, 32), 256, 0, stream>>>(sab, wot, 1024, bo, nullptr, nullptr, nullptr, out);
}

// Round 4
// 269.921 us; speedup vs baseline: 1.4499x; 1.4499x over previous
//
#include <hip/hip_runtime.h>
#include <stdint.h>

typedef unsigned short u16;
typedef short s16x8 __attribute__((ext_vector_type(8)));
typedef unsigned short u16x8 __attribute__((ext_vector_type(8)));
typedef float f32x4 __attribute__((ext_vector_type(4)));

#define GLD16(g, l) __builtin_amdgcn_global_load_lds( \
    (const __attribute__((address_space(1))) uint32_t*)(g), \
    (__attribute__((address_space(3))) uint32_t*)(l), 16, 0, 0)

__device__ __forceinline__ u16 f2bf(float f) {
  uint32_t u = __builtin_bit_cast(uint32_t, f);
  u += 0x7fffu + ((u >> 16) & 1u);
  return (u16)(u >> 16);
}

// 16-lane-row reductions in the VALU pipe via DPP (no DS traffic).
// quad_perm xor1 (0xB1), xor2 (0x4E), then row_ror:4 (0x124), row_ror:8 (0x128).
__device__ __forceinline__ float row16_max(float v) {
  int t;
  t = __builtin_amdgcn_update_dpp(0, __builtin_bit_cast(int, v), 0xB1, 0xF, 0xF, true);
  v = fmaxf(v, __builtin_bit_cast(float, t));
  t = __builtin_amdgcn_update_dpp(0, __builtin_bit_cast(int, v), 0x4E, 0xF, 0xF, true);
  v = fmaxf(v, __builtin_bit_cast(float, t));
  t = __builtin_amdgcn_update_dpp(0, __builtin_bit_cast(int, v), 0x124, 0xF, 0xF, true);
  v = fmaxf(v, __builtin_bit_cast(float, t));
  t = __builtin_amdgcn_update_dpp(0, __builtin_bit_cast(int, v), 0x128, 0xF, 0xF, true);
  v = fmaxf(v, __builtin_bit_cast(float, t));
  return v;
}
__device__ __forceinline__ float row16_sum(float v) {
  int t;
  t = __builtin_amdgcn_update_dpp(0, __builtin_bit_cast(int, v), 0xB1, 0xF, 0xF, true);
  v += __builtin_bit_cast(float, t);
  t = __builtin_amdgcn_update_dpp(0, __builtin_bit_cast(int, v), 0x4E, 0xF, 0xF, true);
  v += __builtin_bit_cast(float, t);
  t = __builtin_amdgcn_update_dpp(0, __builtin_bit_cast(int, v), 0x124, 0xF, 0xF, true);
  v += __builtin_bit_cast(float, t);
  t = __builtin_amdgcn_update_dpp(0, __builtin_bit_cast(int, v), 0x128, 0xF, 0xF, true);
  v += __builtin_bit_cast(float, t);
  return v;
}

// ---------------- cast x (f32 -> bf16), 8 elems/thread ----------------
__global__ void cvt_kernel(const float* __restrict__ in, u16* __restrict__ out) {
  int i = blockIdx.x * 256 + threadIdx.x;
  const float4* p = (const float4*)in + (size_t)i * 2;
  float4 a = p[0], b = p[1];
  u16x8 o;
  o[0] = f2bf(a.x); o[1] = f2bf(a.y); o[2] = f2bf(a.z); o[3] = f2bf(a.w);
  o[4] = f2bf(b.x); o[5] = f2bf(b.y); o[6] = f2bf(b.z); o[7] = f2bf(b.w);
  *((u16x8*)out + i) = o;
}

// ------------- transpose f32 [bz][R][C] -> bf16 [bz][C][R] -------------
__global__ void transpose_f2b(const float* __restrict__ in, u16* __restrict__ out,
                              int R, int C) {
  __shared__ float tile[32][33];
  const int bz = blockIdx.z;
  in  += (size_t)bz * R * C;
  out += (size_t)bz * R * C;
  int c0 = blockIdx.x * 32, r0 = blockIdx.y * 32;
  int tx = threadIdx.x, ty = threadIdx.y;
  #pragma unroll
  for (int i = 0; i < 32; i += 8)
    tile[ty + i][tx] = in[(size_t)(r0 + ty + i) * C + c0 + tx];
  __syncthreads();
  #pragma unroll
  for (int i = 0; i < 32; i += 8)
    out[(size_t)(c0 + ty + i) * R + r0 + tx] = f2bf(tile[tx][ty + i]);
}

// ------------- transpose bf16 [bz][R][C] -> bf16 [bz][C][R] ------------
__global__ void transpose_b2b(const u16* __restrict__ in, u16* __restrict__ out,
                              int R, int C) {
  __shared__ u16 tile[32][33];
  const int bz = blockIdx.z;
  in  += (size_t)bz * R * C;
  out += (size_t)bz * R * C;
  int c0 = blockIdx.x * 32, r0 = blockIdx.y * 32;
  int tx = threadIdx.x, ty = threadIdx.y;
  #pragma unroll
  for (int i = 0; i < 32; i += 8)
    tile[ty + i][tx] = in[(size_t)(r0 + ty + i) * C + c0 + tx];
  __syncthreads();
  #pragma unroll
  for (int i = 0; i < 32; i += 8)
    out[(size_t)(c0 + ty + i) * R + r0 + tx] = tile[tx][ty + i];
}

// ---------------- 128x128x64 bf16 MFMA GEMM (m97 structure) ----------------
template <int EPI>
__global__ __launch_bounds__(256) void gemm128(
    const u16* __restrict__ A, const u16* __restrict__ Bt, int K,
    const float* __restrict__ bias,
    u16* __restrict__ kb, u16* __restrict__ qb, u16* __restrict__ vb,
    float* __restrict__ fout) {
  __shared__ __align__(16) u16 As[128 * 64];
  __shared__ __align__(16) u16 Bs[128 * 64];
  const int tid = threadIdx.x;
  const int lane = tid & 63;
  const int wr = (tid >> 6) >> 1, wc = (tid >> 6) & 1;
  const int row0 = blockIdx.y * 128, col0 = blockIdx.x * 128;
  const int l15 = lane & 15, l4 = lane >> 4;
  const u16* Ablk = A + (size_t)row0 * K;
  const u16* Bblk = Bt + (size_t)col0 * K;
  f32x4 acc[4][4] = {};
  for (int k0 = 0; k0 < K; k0 += 64) {
    #pragma unroll
    for (int i = 0; i < 4; i++) {
      int off = (i * 256 + tid) * 8;
      int r = off >> 6, c = off & 63;
      GLD16(Ablk + (size_t)r * K + k0 + c, As + off);
    }
    #pragma unroll
    for (int i = 0; i < 4; i++) {
      int off = (i * 256 + tid) * 8;
      int r = off >> 6, c = off & 63;
      GLD16(Bblk + (size_t)r * K + k0 + c, Bs + off);
    }
    __syncthreads();
    #pragma unroll
    for (int kc = 0; kc < 2; kc++) {
      s16x8 af[4], bfr[4];
      #pragma unroll
      for (int m = 0; m < 4; m++)
        af[m] = *(const s16x8*)(As + (wr * 64 + m * 16 + l15) * 64 + kc * 32 + l4 * 8);
      #pragma unroll
      for (int n = 0; n < 4; n++)
        bfr[n] = *(const s16x8*)(Bs + (wc * 64 + n * 16 + l15) * 64 + kc * 32 + l4 * 8);
      #pragma unroll
      for (int m = 0; m < 4; m++)
        #pragma unroll
        for (int n = 0; n < 4; n++)
          acc[m][n] = __builtin_amdgcn_mfma_f32_16x16x32_bf16(af[m], bfr[n], acc[m][n], 0, 0, 0);
    }
    __syncthreads();
  }
  const int rbase = row0 + wr * 64;
  const int cbase = col0 + wc * 64;
  if (EPI == 0) {
    #pragma unroll
    for (int n = 0; n < 4; n++) {
      int c = cbase + n * 16 + l15;
      int h = c / 192, rr = c % 192;
      int part = rr >> 6, d = rr & 63;
      float bv = bias[h * 192 + rr];
      u16* dst = (part == 0) ? kb : (part == 1) ? qb : vb;
      // fold 1/sqrt(hd) AND log2(e) (exp2-based softmax) into q
      float sc = (part == 1) ? 0.125f * 1.44269504f : 1.0f;
      #pragma unroll
      for (int m = 0; m < 4; m++)
        #pragma unroll
        for (int i = 0; i < 4; i++) {
          int r = rbase + m * 16 + l4 * 4 + i;
          int b = r >> 11, nn = r & 2047;
          dst[(((size_t)(b * 16 + h) * 2048 + nn) << 6) + d] = f2bf((acc[m][n][i] + bv) * sc);
        }
    }
  } else {
    #pragma unroll
    for (int n = 0; n < 4; n++) {
      int c = cbase + n * 16 + l15;
      float bv = bias[c];
      #pragma unroll
      for (int m = 0; m < 4; m++)
        #pragma unroll
        for (int i = 0; i < 4; i++) {
          int r = rbase + m * 16 + l4 * 4 + i;
          fout[(size_t)r * 1024 + c] = acc[m][n][i] + bv;
        }
    }
  }
}

// ---------------- causal flash attention (v4) ----------------
// QBLK=128 (4 waves x 32 rows, 2 frags/wave), KVBLK=64, LDS-staged K/V with
// XOR-swizzle (linear gload_lds dest + inverse-swizzled global src, rule #21),
// double-buffered with counted vmcnt + raw barriers (T3/T4-lite), DPP softmax
// reductions, atomic work-stealing over 512 descending-size units.
__global__ __launch_bounds__(256, 2) void attn_kernel(
    const u16* __restrict__ q, const u16* __restrict__ k,
    const u16* __restrict__ vt, u16* __restrict__ sa,
    uint32_t* __restrict__ ctr) {
  __shared__ __align__(16) u16 Ks[2][64 * 64];
  __shared__ __align__(16) u16 Vs[2][64 * 64];
  __shared__ __align__(16) u16 Ps[4][2][16][72];
  __shared__ uint32_t s_unit;
  const int tid = threadIdx.x;
  const int lane = tid & 63;
  const int wave = tid >> 6;
  const int l15 = lane & 15, l4 = lane >> 4;

  for (;;) {
    if (tid == 0) s_unit = atomicAdd(ctr, 1u);
    __syncthreads();
    uint32_t u = s_unit;
    if (u >= 512u) break;
    const int bh = (int)(u & 31u);
    const int tile = 15 - (int)(u >> 5);  // descending size
    const int r0 = tile * 128;
    const int ktmax = 2 * tile + 1;
    const int wr0 = r0 + wave * 32;       // frag f rows: wr0+f*16 .. +15

    const u16* kbh = k + (((size_t)bh * 2048) << 6);
    const u16* vbh = vt + (size_t)bh * 64 * 2048;

    // prologue stage of kt=0 into buffer 0 (issue before qf loads)
    #pragma unroll
    for (int i = 0; i < 2; i++) {
      int off = (i * 256 + tid) * 16;  // byte in 8KB tile
      int row = off >> 7;
      int cs = (off & 127) ^ ((row & 7) << 4);
      GLD16(kbh + (((size_t)row) << 6) + (cs >> 1), &Ks[0][0] + (off >> 1));
      GLD16(vbh + (size_t)row * 2048 + (cs >> 1), &Vs[0][0] + (off >> 1));
    }

    // Q fragments (A-frag: row=l15, k=kc*32+l4*8+j)
    s16x8 qf[2][2];
    #pragma unroll
    for (int f = 0; f < 2; f++) {
      const u16* qrow = q + (((size_t)bh * 2048 + wr0 + f * 16 + l15) << 6);
      qf[f][0] = *(const s16x8*)(qrow + l4 * 8);
      qf[f][1] = *(const s16x8*)(qrow + 32 + l4 * 8);
    }

    f32x4 o[2][4] = {};
    float m_[2][4], l_[2][4];
    #pragma unroll
    for (int f = 0; f < 2; f++)
      #pragma unroll
      for (int r = 0; r < 4; r++) { m_[f][r] = -3e38f; l_[f][r] = 0.f; }

    int cur = 0;
    for (int kt = 0; kt <= ktmax; kt++) {
      if (kt < ktmax) {
        // stage kt+1 into the other buffer; loads stay in flight across barrier
        u16* KsB = &Ks[cur ^ 1][0];
        u16* VsB = &Vs[cur ^ 1][0];
        #pragma unroll
        for (int i = 0; i < 2; i++) {
          int off = (i * 256 + tid) * 16;
          int row = off >> 7;
          int cs = (off & 127) ^ ((row & 7) << 4);
          GLD16(kbh + (((size_t)((kt + 1) * 64 + row)) << 6) + (cs >> 1), KsB + (off >> 1));
          GLD16(vbh + (size_t)row * 2048 + (kt + 1) * 64 + (cs >> 1), VsB + (off >> 1));
        }
        asm volatile("s_waitcnt vmcnt(4)" ::: "memory");
      } else {
        asm volatile("s_waitcnt vmcnt(0)" ::: "memory");
      }
      __builtin_amdgcn_s_barrier();
      __builtin_amdgcn_sched_barrier(0);

      const bool live0 = (kt * 64) <= (wr0 + 15);
      const bool live1 = (kt * 64) <= (wr0 + 31);
      if (live0 | live1) {
        const char* Kc = (const char*)&Ks[cur][0];
        const char* Vc = (const char*)&Vs[cur][0];
        const int sw = (l15 & 7) << 4;
        f32x4 s[2][4] = {};
        // S = Q K^T (K-frag reads shared between both q-fragments)
        #pragma unroll
        for (int t = 0; t < 4; t++) {
          int rowb = (t * 16 + l15) << 7;
          s16x8 kf0 = *(const s16x8*)(Kc + rowb + ((l4 * 16) ^ sw));
          s16x8 kf1 = *(const s16x8*)(Kc + rowb + ((64 + l4 * 16) ^ sw));
          if (live0) {
            s[0][t] = __builtin_amdgcn_mfma_f32_16x16x32_bf16(qf[0][0], kf0, s[0][t], 0, 0, 0);
            s[0][t] = __builtin_amdgcn_mfma_f32_16x16x32_bf16(qf[0][1], kf1, s[0][t], 0, 0, 0);
          }
          if (live1) {
            s[1][t] = __builtin_amdgcn_mfma_f32_16x16x32_bf16(qf[1][0], kf0, s[1][t], 0, 0, 0);
            s[1][t] = __builtin_amdgcn_mfma_f32_16x16x32_bf16(qf[1][1], kf1, s[1][t], 0, 0, 0);
          }
        }
        // mask + online softmax (exp2 domain; DPP row reductions)
        #pragma unroll
        for (int f = 0; f < 2; f++) {
          if (!(f ? live1 : live0)) continue;
          const int wr0f = wr0 + f * 16;
          if (kt * 64 + 63 > wr0f) {
            #pragma unroll
            for (int t = 0; t < 4; t++)
              #pragma unroll
              for (int i = 0; i < 4; i++)
                if (kt * 64 + t * 16 + l15 > wr0f + l4 * 4 + i) s[f][t][i] = -3e38f;
          }
          #pragma unroll
          for (int r = 0; r < 4; r++) {
            float sm = fmaxf(fmaxf(s[f][0][r], s[f][1][r]), fmaxf(s[f][2][r], s[f][3][r]));
            sm = row16_max(sm);
            float mn = fmaxf(m_[f][r], sm);
            float al = exp2f(m_[f][r] - mn);
            m_[f][r] = mn;
            float rs = 0.f;
            #pragma unroll
            for (int t = 0; t < 4; t++) {
              float pv = exp2f(s[f][t][r] - mn);
              s[f][t][r] = pv;
              rs += pv;
            }
            rs = row16_sum(rs);
            l_[f][r] = l_[f][r] * al + rs;
            #pragma unroll
            for (int t = 0; t < 4; t++) o[f][t][r] *= al;
          }
          // P (D-layout) -> per-wave LDS -> A-frag (no barrier: wave-private)
          #pragma unroll
          for (int t = 0; t < 4; t++)
            #pragma unroll
            for (int r = 0; r < 4; r++)
              Ps[wave][f][l4 * 4 + r][t * 16 + l15] = f2bf(s[f][t][r]);
        }
        s16x8 pa[2][2];
        #pragma unroll
        for (int f = 0; f < 2; f++) {
          if (!(f ? live1 : live0)) continue;
          pa[f][0] = *(const s16x8*)&Ps[wave][f][l15][l4 * 8];
          pa[f][1] = *(const s16x8*)&Ps[wave][f][l15][32 + l4 * 8];
        }
        // O += P V (V-frag reads shared between both fragments)
        #pragma unroll
        for (int t = 0; t < 4; t++) {
          int rowb = (t * 16 + l15) << 7;
          s16x8 vf0 = *(const s16x8*)(Vc + rowb + ((l4 * 16) ^ sw));
          s16x8 vf1 = *(const s16x8*)(Vc + rowb + ((64 + l4 * 16) ^ sw));
          if (live0) {
            o[0][t] = __builtin_amdgcn_mfma_f32_16x16x32_bf16(pa[0][0], vf0, o[0][t], 0, 0, 0);
            o[0][t] = __builtin_amdgcn_mfma_f32_16x16x32_bf16(pa[0][1], vf1, o[0][t], 0, 0, 0);
          }
          if (live1) {
            o[1][t] = __builtin_amdgcn_mfma_f32_16x16x32_bf16(pa[1][0], vf0, o[1][t], 0, 0, 0);
            o[1][t] = __builtin_amdgcn_mfma_f32_16x16x32_bf16(pa[1][1], vf1, o[1][t], 0, 0, 0);
          }
        }
      }
      asm volatile("" ::: "memory");
      __builtin_amdgcn_sched_barrier(0);
      __builtin_amdgcn_s_barrier();  // protect cur from restage next iter
      cur ^= 1;
    }
    // epilogue: normalize, write sa[b][n][h*64+d]
    const int b = bh >> 4, h = bh & 15;
    #pragma unroll
    for (int f = 0; f < 2; f++)
      #pragma unroll
      for (int r = 0; r < 4; r++) {
        float inv = 1.f / l_[f][r];
        int n = wr0 + f * 16 + l4 * 4 + r;
        u16* dst = sa + ((size_t)(b * 2048 + n) << 10) + h * 64;
        #pragma unroll
        for (int t = 0; t < 4; t++)
          dst[t * 16 + l15] = f2bf(o[f][t][r] * inv);
      }
  }
}

extern "C" void kernel_launch(void* const* d_in, const int* in_sizes, int n_in,
                              void* d_out, int out_size, void* d_ws, size_t ws_size,
                              hipStream_t stream) {
  const float* x    = (const float*)d_in[0];
  const float* Wqkv = (const float*)d_in[1];
  const float* bqkv = (const float*)d_in[2];
  const float* Wo   = (const float*)d_in[3];
  const float* bo   = (const float*)d_in[4];
  float* out = (float*)d_out;

  // workspace carve (u16 elements)
  u16* xb  = (u16*)d_ws;          // [4096][1024] (reused as sab after qkv gemm)
  u16* wqt = xb + 4194304;        // [16*192][1024]  (B^T for qkv gemm)
  u16* wot = wqt + 3145728;       // [1024][1024]    (B^T for out gemm)
  u16* qb  = wot + 1048576;       // [32][2048][64]
  u16* kb  = qb + 4194304;
  u16* vb  = kb + 4194304;
  u16* vtb = vb + 4194304;        // [32][64][2048]
  u16* sab = xb;                  // alias: x's bf16 copy dead after qkv gemm
  uint32_t* ctr = (uint32_t*)wqt; // alias: wqt dead after qkv gemm

  cvt_kernel<<<2048, 256, 0, stream>>>(x, xb);
  transpose_f2b<<<dim3(6, 32, 16), dim3(32, 8), 0, stream>>>(Wqkv, wqt, 1024, 192);
  transpose_f2b<<<dim3(32, 32, 1), dim3(32, 8), 0, stream>>>(Wo, wot, 1024, 1024);
  gemm128<0><<<dim3(24, 32), 256, 0, stream>>>(xb, wqt, 1024, bqkv, kb, qb, vb, nullptr);
  transpose_b2b<<<dim3(2, 64, 32), dim3(32, 8), 0, stream>>>(vb, vtb, 2048, 64);
  hipMemsetAsync(ctr, 0, sizeof(uint32_t), stream);
  attn_kernel<<<dim3(448), 256, 0, stream>>>(qb, kb, vtb, sab, ctr);
  gemm128<1><<<dim3(8, 32), 256, 0, stream>>>(sab, wot, 1024, bo, nullptr, nullptr, nullptr, out);
}